// Round 6
// baseline (316.056 us; speedup 1.0000x reference)
//
#include <hip/hip_runtime.h>
#include <cstdint>

typedef __attribute__((ext_vector_type(8))) short bf16x8;   // 8 x bf16 (4 VGPR)
typedef __attribute__((ext_vector_type(4))) float f32x4;    // MFMA 16x16 acc
typedef __attribute__((ext_vector_type(4))) int   i32x4;

__device__ __forceinline__ unsigned short f2bf(float x) {   // RNE fp32->bf16
  unsigned u = __float_as_uint(x);
  u += 0x7fffu + ((u >> 16) & 1u);
  return (unsigned short)(u >> 16);
}
__device__ __forceinline__ float bf2f(unsigned short h) {
  return __uint_as_float(((unsigned)h) << 16);
}
__device__ __forceinline__ float silu_f(float v) {
  return v * __builtin_amdgcn_rcpf(1.0f + __expf(-v));
}
__device__ __forceinline__ unsigned pk2bf(float lo, float hi) {
#if defined(__has_builtin)
#if __has_builtin(__builtin_amdgcn_cvt_pk_bf16_f32)
  auto v = __builtin_amdgcn_cvt_pk_bf16_f32(lo, hi);
  unsigned u; __builtin_memcpy(&u, &v, 4); return u;
#else
  return ((unsigned)f2bf(hi) << 16) | (unsigned)f2bf(lo);
#endif
#else
  return ((unsigned)f2bf(hi) << 16) | (unsigned)f2bf(lo);
#endif
}
__device__ __forceinline__ unsigned lo_pack(unsigned x, unsigned y) {
  return __builtin_amdgcn_perm(y, x, 0x05040100u);   // x.lo16 | y.lo16<<16
}
__device__ __forceinline__ unsigned hi_pack(unsigned x, unsigned y) {
  return __builtin_amdgcn_perm(y, x, 0x07060302u);
}

// ---- pack W into 16x16x32 MFMA B-frag order, bf16. K0 padded 134->160.
// layout (shorts): [layer][g(64cols)][kt(32k)][nt(16cols)][lane(64)][j(8)]
// B-frag: n = lane&15, k = (lane>>4)*8 + j.
// One block per (layer, kt) 32-row slab: 5 + 8 + 8 = 21 blocks, 512 thr.
__global__ void pack_kernel(const float* __restrict__ W0, const float* __restrict__ W1,
                            const float* __restrict__ W2,
                            unsigned short* __restrict__ packW) {
  __shared__ float ldsF[32][257];
  const int s = blockIdx.x, tid = threadIdx.x;
  const float* W; int KT, kmax, base, kt;
  if (s < 5)       { W = W0; KT = 5; kmax = 134; base = 0;      kt = s; }
  else if (s < 13) { W = W1; KT = 8; kmax = 256; base = 40960;  kt = s - 5; }
  else             { W = W2; KT = 8; kmax = 256; base = 106496; kt = s - 13; }
#pragma unroll
  for (int i = 0; i < 16; ++i) {                  // 32 x 256 floats, coalesced
    const int idx = i * 512 + tid;
    const int kl = idx >> 8, col = idx & 255;
    const int kg = kt * 32 + kl;
    ldsF[kl][col] = (kg < kmax) ? W[kg * 256 + col] : 0.0f;
  }
  __syncthreads();
#pragma unroll
  for (int half = 0; half < 2; ++half) {          // 1024 fragments, 2 per thread
    const int f = half * 512 + tid;
    const int g = f >> 8, nt = (f >> 6) & 3, l = f & 63;
    const int col = g * 64 + nt * 16 + (l & 15);
    const int kb = (l >> 4) * 8;
    i32x4 v = { (int)pk2bf(ldsF[kb + 0][col], ldsF[kb + 1][col]),
                (int)pk2bf(ldsF[kb + 2][col], ldsF[kb + 3][col]),
                (int)pk2bf(ldsF[kb + 4][col], ldsF[kb + 5][col]),
                (int)pk2bf(ldsF[kb + 6][col], ldsF[kb + 7][col]) };
    *(i32x4*)(packW + base + g * (KT * 2048) + kt * 2048 + nt * 512 + l * 8) = v;
  }
}

// ---------------- one GCN layer: 16 waves x 16 nodes, 2 phases of 128 cols --------
// Identity node map: C/D row i (lane quad Q=i>>2, reg r=i&3) = node 16w + i.
// A-frag: m = lane&15 = node-local, k = (lane>>4)*8 + j.
template <int KT, int LAYER>
__device__ __forceinline__ void gcn_layer(
    const int w, const int lane, const int Q, const int cl,
    const int up, const int dn,
    const unsigned short* __restrict__ packL, const float* __restrict__ BIAS,
    const bf16x8* Aold, bf16x8* Anew,
    unsigned short* bnd, unsigned int* scrw, float* poolw) {
  const float T = 0.33333333333f;
#pragma unroll
  for (int h = 0; h < 2; ++h) {
    const bf16x8* wbase = (const bf16x8*)packL;
    f32x4 acc[8];
#pragma unroll
    for (int n8 = 0; n8 < 8; ++n8)
#pragma unroll
      for (int r = 0; r < 4; ++r) acc[n8][r] = 0.f;
    // K-loop: 128 cols (8 n-tiles), all B from global (L1/L2-resident weights)
#pragma unroll
    for (int kt = 0; kt < KT; ++kt) {
#pragma unroll
      for (int n8 = 0; n8 < 8; ++n8) {
        const int g = 2 * h + (n8 >> 2), nt = n8 & 3;
        bf16x8 bf = wbase[(g * KT + kt) * 256 + nt * 64 + lane];
        acc[n8] = __builtin_amdgcn_mfma_f32_16x16x32_bf16(Aold[kt], bf, acc[n8], 0, 0, 0);
      }
    }

    // publish wave-edge nodes (row0 @ Q==0 r0, row15 @ Q==3 r3) into parity buffer
    unsigned short* bndp = bnd + (h & 1) * 4096;
    if (Q == 0) {
#pragma unroll
      for (int n8 = 0; n8 < 8; ++n8)
        bndp[(w * 2 + 0) * 128 + n8 * 16 + cl] = f2bf(acc[n8][0]);
    } else if (Q == 3) {
#pragma unroll
      for (int n8 = 0; n8 < 8; ++n8)
        bndp[(w * 2 + 1) * 128 + n8 * 16 + cl] = f2bf(acc[n8][3]);
    }
    __syncthreads();   // the single per-phase barrier

    // epilogue: cyclic 3-tap + bias + silu; per 64-col chunk: transpose -> A-frags
    auto comp = [&](int n8, float* y) {
      float nxt = __shfl(acc[n8][0], up);   // node 4Q+4 (valid Q<3)
      float prv = __shfl(acc[n8][3], dn);   // node 4Q-1 (valid Q>0)
      if (Q == 0) prv = bf2f(bndp[(((w + 15) & 15) * 2 + 1) * 128 + n8 * 16 + cl]);
      if (Q == 3) nxt = bf2f(bndp[(((w + 1) & 15) * 2 + 0) * 128 + n8 * 16 + cl]);
      const float bias = BIAS[h * 128 + n8 * 16 + cl];
      const float v0 = (prv        + acc[n8][0] + acc[n8][1]) * T + bias;
      const float v1 = (acc[n8][0] + acc[n8][1] + acc[n8][2]) * T + bias;
      const float v2 = (acc[n8][1] + acc[n8][2] + acc[n8][3]) * T + bias;
      const float v3 = (acc[n8][2] + acc[n8][3] + nxt)        * T + bias;
      y[0] = silu_f(v0); y[1] = silu_f(v1); y[2] = silu_f(v2); y[3] = silu_f(v3);
    };
#pragma unroll
    for (int cg = 0; cg < 2; ++cg) {
      if constexpr (LAYER == 2) {
#pragma unroll
        for (int t = 0; t < 4; ++t) {
          float y[4];
          comp(cg * 4 + t, y);
          float s = y[0] + y[1] + y[2] + y[3];
          s += __shfl_xor(s, 16);
          s += __shfl_xor(s, 32);
          if (lane < 16) poolw[w * 256 + h * 128 + (cg * 4 + t) * 16 + lane] = s;
        }
      } else {
        // scr rows = node-local, dword d holds col pair (64c+d, 64c+d+32); stride 36
#pragma unroll
        for (int t = 0; t < 2; ++t) {
          float ya[4], yb[4];
          comp(cg * 4 + t, ya);
          comp(cg * 4 + t + 2, yb);
#pragma unroll
          for (int r = 0; r < 4; ++r)
            scrw[(4 * Q + r) * 36 + t * 16 + cl] = pk2bf(ya[r], yb[r]);
        }
        // rebuild next-layer A-frags (same-wave DS, in-order -> no barrier)
        const unsigned int* sb = scrw + cl * 36;
        uint4 da = *(const uint4*)(sb + 8 * Q);
        uint4 db = *(const uint4*)(sb + 8 * Q + 4);
        i32x4 lo = { (int)lo_pack(da.x, da.y), (int)lo_pack(da.z, da.w),
                     (int)lo_pack(db.x, db.y), (int)lo_pack(db.z, db.w) };
        i32x4 hi = { (int)hi_pack(da.x, da.y), (int)hi_pack(da.z, da.w),
                     (int)hi_pack(db.x, db.y), (int)hi_pack(db.z, db.w) };
        const int ktp = 2 * (2 * h + cg);
        Anew[ktp]     = __builtin_bit_cast(bf16x8, lo);
        Anew[ktp + 1] = __builtin_bit_cast(bf16x8, hi);
      }
    }
  }
}

// ---------------- main fused kernel: 1 block = 1 graph, 16 waves x 16 nodes --------
__global__ __launch_bounds__(1024, 4) void poly_kernel(
    const float* __restrict__ x, const float* __restrict__ t,
    const float* __restrict__ tw, const float* __restrict__ tb,
    const unsigned short* __restrict__ packW,
    const float* __restrict__ B0, const float* __restrict__ B1,
    const float* __restrict__ B2, float* __restrict__ out) {
  __shared__ __align__(16) unsigned short bnd[8192];     // 16 KiB: 2 parity x 16w x 2 x 128
  __shared__ __align__(16) unsigned int   scr3[16 * 576];// 36 KiB per-wave transpose / pool
  __shared__ __align__(16) unsigned short temb_sh[160];  // padded time embedding (bf16)

  const int tid = threadIdx.x;
  const int w = tid >> 6, lane = tid & 63;
  const int Q = lane >> 4, cl = lane & 15;
  const int up = (lane + 16) & 63, dn = (lane - 16) & 63;
  const int b = blockIdx.x;

  // ---- fused time MLP: temb = silu(sinemb(t[b]) @ tw + tb), pad [0 x6, ., 0 x26] ----
  {
    float* e_sh = (float*)bnd;        // 128 floats
    float* part = (float*)scr3;       // 1024 float partials
    if (tid < 128) {
      const float tv = t[b];
      const int i = tid & 63;
      const float f = expf(-0.14619588396823767f * (float)i);  // log(1e4)/63
      const float ang = tv * f;
      e_sh[tid] = (tid < 64) ? sinf(ang) : cosf(ang);
    }
    __syncthreads();
    {
      const int j = tid & 127, p = tid >> 7;   // 8-way k-split over the block
      float a = 0.f;
#pragma unroll 8
      for (int kk = 0; kk < 16; ++kk) {
        const int k = p * 16 + kk;
        a += e_sh[k] * tw[k * 128 + j];
      }
      part[p * 128 + j] = a;
    }
    __syncthreads();
    if (tid < 128) {
      float a = tb[tid];
#pragma unroll
      for (int pp = 0; pp < 8; ++pp) a += part[pp * 128 + tid];
      temb_sh[6 + tid] = f2bf(silu_f(a));
      if (tid < 6) temb_sh[tid] = 0;
    } else if (tid < 154) {
      temb_sh[6 + tid] = 0;                    // zeros at 134..159
    }
    __syncthreads();
  }

  // layer-0 A frags: [coords(2), pe(4), temb(128), 0(26)] = K 160, 5 k-tiles
  bf16x8 A0[5], A1[8], A2[8];
  {
#pragma unroll
    for (int kt = 0; kt < 5; ++kt)
      A0[kt] = *(const bf16x8*)(temb_sh + kt * 32 + Q * 8);
    if (Q == 0) {  // k=0..5 live in Q==0 lanes of k-tile 0; A row m=cl = node 16w+cl
      const int n = w * 16 + cl;
      const float2 xy = ((const float2*)x)[b * 256 + n];
      const float th = 0.024543692605870074f * (float)n;   // 2*pi/256
      A0[0][0] = (short)f2bf(xy.x);
      A0[0][1] = (short)f2bf(xy.y);
      A0[0][2] = (short)f2bf(sinf(th));
      A0[0][3] = (short)f2bf(cosf(th));
      A0[0][4] = (short)f2bf(sinf(2.f * th));
      A0[0][5] = (short)f2bf(cosf(2.f * th));
    }
  }

  unsigned int* scrw = scr3 + w * 576;
  float* poolw = (float*)scr3;   // layer-2 per-wave pool partials (transpose dead by then)
  gcn_layer<5, 0>(w, lane, Q, cl, up, dn, packW,          B0, A0, A1, bnd, scrw, poolw);
  gcn_layer<8, 1>(w, lane, Q, cl, up, dn, packW + 40960,  B1, A1, A2, bnd, scrw, poolw);
  gcn_layer<8, 2>(w, lane, Q, cl, up, dn, packW + 106496, B2, A2, A1, bnd, scrw, poolw);

  __syncthreads();
  if (tid < 256) {
    float s = 0.f;
#pragma unroll
    for (int ww = 0; ww < 16; ++ww) s += poolw[ww * 256 + tid];
    out[b * 256 + tid] = s * (1.f / 256.f);
  }
}

// ---------------- launch ----------------
extern "C" void kernel_launch(void* const* d_in, const int* in_sizes, int n_in,
                              void* d_out, int out_size, void* d_ws, size_t ws_size,
                              hipStream_t stream) {
  const float* x  = (const float*)d_in[0];
  const float* t  = (const float*)d_in[1];
  const float* tw = (const float*)d_in[2];
  const float* tb = (const float*)d_in[3];
  const float* W0 = (const float*)d_in[4];
  const float* b0 = (const float*)d_in[5];
  const float* W1 = (const float*)d_in[6];
  const float* b1 = (const float*)d_in[7];
  const float* W2 = (const float*)d_in[8];
  const float* b2 = (const float*)d_in[9];

  unsigned short* packW = (unsigned short*)d_ws;   // 172032 shorts (L0:40960, L1/L2:65536)
  float* out = (float*)d_out;

  pack_kernel<<<21, 512, 0, stream>>>(W0, W1, W2, packW);
  poly_kernel<<<1024, 1024, 0, stream>>>(x, t, tw, tb, packW, b0, b1, b2, out);
}

// Round 7
// 211.106 us; speedup vs baseline: 1.4971x; 1.4971x over previous
//
#include <hip/hip_runtime.h>
#include <cstdint>

typedef __attribute__((ext_vector_type(8)))  short bf16x8;   // 8 x bf16 (4 VGPR)
typedef __attribute__((ext_vector_type(16))) float f32x16;   // MFMA 32x32 acc
typedef __attribute__((ext_vector_type(2)))  float f32x2;
typedef __attribute__((ext_vector_type(4)))  int   i32x4;

__device__ __forceinline__ unsigned short f2bf(float x) {    // RNE fp32->bf16
  unsigned u = __float_as_uint(x);
  u += 0x7fffu + ((u >> 16) & 1u);
  return (unsigned short)(u >> 16);
}
__device__ __forceinline__ float bf2f(unsigned short h) {
  return __uint_as_float(((unsigned)h) << 16);
}
__device__ __forceinline__ float silu_f(float v) {
  return v * __builtin_amdgcn_rcpf(1.0f + __expf(-v));
}
__device__ __forceinline__ unsigned pk2bf(float lo, float hi) {
#if defined(__has_builtin)
#if __has_builtin(__builtin_amdgcn_cvt_pk_bf16_f32)
  auto v = __builtin_amdgcn_cvt_pk_bf16_f32(lo, hi);
  unsigned u; __builtin_memcpy(&u, &v, 4); return u;
#else
  return ((unsigned)f2bf(hi) << 16) | (unsigned)f2bf(lo);
#endif
#else
  return ((unsigned)f2bf(hi) << 16) | (unsigned)f2bf(lo);
#endif
}
__device__ __forceinline__ unsigned lo_pack(unsigned x, unsigned y) {
  return __builtin_amdgcn_perm(y, x, 0x05040100u);   // x.lo16 | y.lo16<<16
}
__device__ __forceinline__ unsigned hi_pack(unsigned x, unsigned y) {
  return __builtin_amdgcn_perm(y, x, 0x07060302u);
}

// ---- pack W0/W1/W2 into MFMA B-frag order via LDS transpose (coalesced R+W).
// dest layout: [layer][g(64 cols)][t(32-col tile)][kt][lane][8], K0 padded 134->144.
__global__ void pack_kernel(const float* __restrict__ W0, const float* __restrict__ W1,
                            const float* __restrict__ W2,
                            unsigned short* __restrict__ packW) {
  __shared__ float ldsF[16][257];
  const int s = blockIdx.x, tid = threadIdx.x;
  const float* W; int KT, kmax, base, kt;
  if (s < 9)       { W = W0; KT = 9;  kmax = 134; base = 0;      kt = s; }
  else if (s < 25) { W = W1; KT = 16; kmax = 256; base = 36864;  kt = s - 9; }
  else             { W = W2; KT = 16; kmax = 256; base = 102400; kt = s - 25; }
  const int k0 = kt * 16;
#pragma unroll
  for (int i = 0; i < 8; ++i) {                 // 512 thr x 8 = 16 x 256 floats
    const int idx = i * 512 + tid;
    const int kl = idx >> 8, col = idx & 255;
    const int kg = k0 + kl;
    ldsF[kl][col] = (kg < kmax) ? W[kg * 256 + col] : 0.0f;   // coalesced rows
  }
  __syncthreads();
  const int g = tid >> 7, t = (tid >> 6) & 1, lane = tid & 63;
  const int col = g * 64 + t * 32 + (lane & 31);
  const int kb = 8 * (lane >> 5);
  unsigned u0 = pk2bf(ldsF[kb + 0][col], ldsF[kb + 1][col]);
  unsigned u1 = pk2bf(ldsF[kb + 2][col], ldsF[kb + 3][col]);
  unsigned u2 = pk2bf(ldsF[kb + 4][col], ldsF[kb + 5][col]);
  unsigned u3 = pk2bf(ldsF[kb + 6][col], ldsF[kb + 7][col]);
  unsigned short* dst = packW + base + g * (KT * 1024) + t * (KT * 512) + kt * 512 + lane * 8;
  i32x4 v = { (int)u0, (int)u1, (int)u2, (int)u3 };
  *(i32x4*)dst = v;
}

// ---------------- one GCN layer, wave-dataflow (NO barriers) ----------------
// Node map: A-row m holds node 32w + sig(m), sig(m)=(m&3)+4((m>>3)&3)+16((m>>2)&1)
// => C/D reg r of lane (q,c) = node 32w + 16q + r.
// Boundary exchange: per (epoch,wave) dedicated LDS slot + release/acquire flag;
// wave w only waits on waves w-1 / w+1 (local dataflow, deadlock-free DAG).
template <int KT, int LAYER>
__device__ __forceinline__ void gcn_layer(
    const int w, const int lane, const int q, const int c, const int sig,
    const int wp, const int wn, const int ebase,
    const unsigned short* __restrict__ packL,
    const float* __restrict__ BIAS,
    const bf16x8* Aold, bf16x8* Anew,
    unsigned short* bndE, unsigned int* flagsL,
    unsigned int* scr3_w, float* poolw) {
#pragma unroll
  for (int g = 0; g < 4; ++g) {
    const int e = ebase + g;
    const unsigned short* srcg = packL + g * (KT * 1024);

    // K-loop: both B tiles streamed from global (L1/L2-resident), A in registers
    f32x16 acc0, acc1;
#pragma unroll
    for (int i = 0; i < 16; ++i) { acc0[i] = 0.f; acc1[i] = 0.f; }
    {
      const bf16x8* wb0 = (const bf16x8*)srcg;
      const bf16x8* wb1 = (const bf16x8*)(srcg + KT * 512);
#pragma unroll
      for (int kt = 0; kt < KT; ++kt) {
        bf16x8 b0 = wb0[kt * 64 + lane];
        bf16x8 b1 = wb1[kt * 64 + lane];
        acc0 = __builtin_amdgcn_mfma_f32_32x32x16_bf16(Aold[kt], b0, acc0, 0, 0, 0);
        acc1 = __builtin_amdgcn_mfma_f32_32x32x16_bf16(Aold[kt], b1, acc1, 0, 0, 0);
      }
    }

    // ---- produce: write this wave's boundary rows into its epoch slot, then flag
    {
      unsigned short* myb = bndE + (e * 8 + w) * 128;
      if (q == 0) { myb[c]      = f2bf(acc0[0]);  myb[32 + c] = f2bf(acc1[0]);  }
      else        { myb[64 + c] = f2bf(acc0[15]); myb[96 + c] = f2bf(acc1[15]); }
      if (lane == 0)
        __hip_atomic_store(&flagsL[e * 8 + w], 1u, __ATOMIC_RELEASE,
                           __HIP_MEMORY_SCOPE_WORKGROUP);
    }

    // cross-half edges within the wave (independent of neighbors)
    const float e0t0  = __shfl_xor(acc0[0], 32);
    const float e0t1  = __shfl_xor(acc1[0], 32);
    const float e15t0 = __shfl_xor(acc0[15], 32);
    const float e15t1 = __shfl_xor(acc1[15], 32);

    // ---- consume: wait only on neighbors' flags for this epoch
#pragma clang loop unroll(disable)
    while (__hip_atomic_load(&flagsL[e * 8 + wp], __ATOMIC_ACQUIRE,
                             __HIP_MEMORY_SCOPE_WORKGROUP) == 0u)
      __builtin_amdgcn_s_sleep(1);
#pragma clang loop unroll(disable)
    while (__hip_atomic_load(&flagsL[e * 8 + wn], __ATOMIC_ACQUIRE,
                             __HIP_MEMORY_SCOPE_WORKGROUP) == 0u)
      __builtin_amdgcn_s_sleep(1);

    const float bp0 = bf2f(bndE[(e * 8 + wp) * 128 + 64 + c]);   // node 32w-1
    const float bp1 = bf2f(bndE[(e * 8 + wp) * 128 + 96 + c]);
    const float bn0 = bf2f(bndE[(e * 8 + wn) * 128 + c]);        // node 32w+32
    const float bn1 = bf2f(bndE[(e * 8 + wn) * 128 + 32 + c]);
    const float bias0 = BIAS[g * 64 + c], bias1 = BIAS[g * 64 + 32 + c];
    const float T = 0.33333333333f;
    float ps0 = 0.f, ps1 = 0.f;
#pragma unroll
    for (int r = 0; r < 16; ++r) {
      float pr0, pr1, nx0, nx1;
      if (r > 0)       { pr0 = acc0[r - 1]; pr1 = acc1[r - 1]; }
      else             { pr0 = q ? e15t0 : bp0; pr1 = q ? e15t1 : bp1; }
      if (r < 15)      { nx0 = acc0[r + 1]; nx1 = acc1[r + 1]; }
      else             { nx0 = q ? bn0 : e0t0; nx1 = q ? bn1 : e0t1; }
      f32x2 v2;
      v2.x = (pr0 + acc0[r] + nx0) * T + bias0;
      v2.y = (pr1 + acc1[r] + nx1) * T + bias1;
      f32x2 ex; ex.x = __expf(-v2.x); ex.y = __expf(-v2.y);
      f32x2 den = ex + 1.0f;
      f32x2 y2;
      y2.x = v2.x * __builtin_amdgcn_rcpf(den.x);
      y2.y = v2.y * __builtin_amdgcn_rcpf(den.y);
      if constexpr (LAYER == 2) { ps0 += y2.x; ps1 += y2.y; }
      else {
        scr3_w[(16 * q + r) * 34 + c] = pk2bf(y2.x, y2.y);  // row = node-local idx
      }
    }

    if constexpr (LAYER == 2) {
      ps0 += __shfl_xor(ps0, 32);
      ps1 += __shfl_xor(ps1, 32);
      if (q == 0) { poolw[w * 256 + g * 64 + c]      = ps0;
                    poolw[w * 256 + g * 64 + 32 + c] = ps1; }
    } else {
      // rebuild next-layer A-frags (same-wave DS, in-order -> no sync needed)
      const unsigned int* sb = scr3_w + sig * 34;
      uint2 d0 = *(const uint2*)(sb + 8 * q + 0);
      uint2 d1 = *(const uint2*)(sb + 8 * q + 2);
      uint2 d2 = *(const uint2*)(sb + 8 * q + 4);
      uint2 d3 = *(const uint2*)(sb + 8 * q + 6);
      uint2 e0 = *(const uint2*)(sb + 16 + 8 * q + 0);
      uint2 e1 = *(const uint2*)(sb + 16 + 8 * q + 2);
      uint2 e2 = *(const uint2*)(sb + 16 + 8 * q + 4);
      uint2 e3 = *(const uint2*)(sb + 16 + 8 * q + 6);
      i32x4 f0 = { (int)lo_pack(d0.x, d0.y), (int)lo_pack(d1.x, d1.y),
                   (int)lo_pack(d2.x, d2.y), (int)lo_pack(d3.x, d3.y) };
      i32x4 f1 = { (int)lo_pack(e0.x, e0.y), (int)lo_pack(e1.x, e1.y),
                   (int)lo_pack(e2.x, e2.y), (int)lo_pack(e3.x, e3.y) };
      i32x4 f2v = { (int)hi_pack(d0.x, d0.y), (int)hi_pack(d1.x, d1.y),
                    (int)hi_pack(d2.x, d2.y), (int)hi_pack(d3.x, d3.y) };
      i32x4 f3 = { (int)hi_pack(e0.x, e0.y), (int)hi_pack(e1.x, e1.y),
                   (int)hi_pack(e2.x, e2.y), (int)hi_pack(e3.x, e3.y) };
      Anew[g * 4 + 0] = __builtin_bit_cast(bf16x8, f0);
      Anew[g * 4 + 1] = __builtin_bit_cast(bf16x8, f1);
      Anew[g * 4 + 2] = __builtin_bit_cast(bf16x8, f2v);
      Anew[g * 4 + 3] = __builtin_bit_cast(bf16x8, f3);
    }
  }
}

// ---------------- main fused kernel: 1 block = 1 graph, 8 waves x 32 nodes ----------
__global__ __launch_bounds__(512, 2) void poly_kernel(
    const float* __restrict__ x, const float* __restrict__ t,
    const float* __restrict__ tw, const float* __restrict__ tb,
    const unsigned short* __restrict__ packW,
    const float* __restrict__ B0, const float* __restrict__ B1,
    const float* __restrict__ B2, float* __restrict__ out) {
  __shared__ __align__(16) unsigned short bndE[12288];   // 24 KiB: 12 epochs x 8 w x 2 x 64
  __shared__ unsigned int flagsL[96];                    // per-(epoch,wave) flags
  __shared__ __align__(16) unsigned int   scr3[8 * 1088];// 34 KiB per-wave transpose
  __shared__ float poolL[2048];                          //  8 KiB per-wave pool partials
  __shared__ __align__(16) unsigned short temb_sh[160];  // padded time embedding (bf16)

  const int tid = threadIdx.x;
  const int w = tid >> 6, lane = tid & 63;
  const int q = lane >> 5, c = lane & 31;
  const int wp = (w + 7) & 7, wn = (w + 1) & 7;
  const int b = blockIdx.x;
  const int sig = (c & 3) + 4 * ((c >> 3) & 3) + 16 * ((c >> 2) & 1);

  // zero this wave's 12 epoch flags (published by the MLP's first barrier)
  if (lane < 12) flagsL[lane * 8 + w] = 0;

  // ---- fused time MLP: temb = silu(sinemb(t[b]) @ tw + tb), padded [0x6, ., 0x10] ----
  {
    float* e_sh = (float*)bndE;       // 128 floats scratch (epoch data written later)
    float* part = (float*)scr3;       // 512 float partials
    if (tid < 128) {
      const float tv = t[b];
      const int i = tid & 63;
      const float f = expf(-0.14619588396823767f * (float)i);  // log(1e4)/63
      const float ang = tv * f;
      e_sh[tid] = (tid < 64) ? sinf(ang) : cosf(ang);
    }
    __syncthreads();
    {
      const int j = tid & 127, p = tid >> 7;   // 4-way k-split over the block
      float a = 0.f;
#pragma unroll 8
      for (int kk = 0; kk < 32; ++kk) {
        const int k = p * 32 + kk;
        a += e_sh[k] * tw[k * 128 + j];
      }
      part[tid] = a;
    }
    __syncthreads();
    if (tid < 128) {
      const float a = tb[tid] + part[tid] + part[128 + tid] + part[256 + tid] + part[384 + tid];
      temb_sh[6 + tid] = f2bf(silu_f(a));
      if (tid < 6)  temb_sh[tid] = 0;
      if (tid < 10) temb_sh[134 + tid] = 0;
    }
    __syncthreads();   // temb + zeroed flags visible to all waves
  }

  // layer-0 A frags: [coords(2), pe(4), temb(128), pad0(10)] = K 144
  bf16x8 A0[9], A1[16], A2[16];
  {
#pragma unroll
    for (int kt = 0; kt < 9; ++kt)
      A0[kt] = *(const bf16x8*)(temb_sh + kt * 16 + q * 8);
    if (q == 0) {  // k=0..5 live in q==0 lanes of k-tile 0; A-row m=c holds node 32w+sig
      const int n = w * 32 + sig;
      const float2 xy = ((const float2*)x)[b * 256 + n];
      const float th = 0.024543692605870074f * (float)n;   // 2*pi/256
      A0[0][0] = (short)f2bf(xy.x);
      A0[0][1] = (short)f2bf(xy.y);
      A0[0][2] = (short)f2bf(sinf(th));
      A0[0][3] = (short)f2bf(cosf(th));
      A0[0][4] = (short)f2bf(sinf(2.f * th));
      A0[0][5] = (short)f2bf(cosf(2.f * th));
    }
  }

  unsigned int* scr3_w = scr3 + w * 1088;
  gcn_layer< 9, 0>(w, lane, q, c, sig, wp, wn, 0, packW,          B0, A0, A1,
                   bndE, flagsL, scr3_w, poolL);
  gcn_layer<16, 1>(w, lane, q, c, sig, wp, wn, 4, packW + 36864,  B1, A1, A2,
                   bndE, flagsL, scr3_w, poolL);
  gcn_layer<16, 2>(w, lane, q, c, sig, wp, wn, 8, packW + 102400, B2, A2, A1,
                   bndE, flagsL, scr3_w, poolL);

  __syncthreads();   // the single closing barrier before the pooled reduction
  if (tid < 256) {
    float s = 0.f;
#pragma unroll
    for (int ww = 0; ww < 8; ++ww) s += poolL[ww * 256 + tid];
    out[b * 256 + tid] = s * (1.f / 256.f);
  }
}

// ---------------- launch ----------------
extern "C" void kernel_launch(void* const* d_in, const int* in_sizes, int n_in,
                              void* d_out, int out_size, void* d_ws, size_t ws_size,
                              hipStream_t stream) {
  const float* x  = (const float*)d_in[0];
  const float* t  = (const float*)d_in[1];
  const float* tw = (const float*)d_in[2];
  const float* tb = (const float*)d_in[3];
  const float* W0 = (const float*)d_in[4];
  const float* b0 = (const float*)d_in[5];
  const float* W1 = (const float*)d_in[6];
  const float* b1 = (const float*)d_in[7];
  const float* W2 = (const float*)d_in[8];
  const float* b2 = (const float*)d_in[9];

  unsigned short* packW = (unsigned short*)d_ws;   // 167936 shorts
  float* out = (float*)d_out;

  pack_kernel<<<41, 512, 0, stream>>>(W0, W1, W2, packW);
  poly_kernel<<<1024, 512, 0, stream>>>(x, t, tw, tb, packW, b0, b1, b2, out);
}

// Round 8
// 201.944 us; speedup vs baseline: 1.5651x; 1.0454x over previous
//
#include <hip/hip_runtime.h>
#include <cstdint>

typedef __attribute__((ext_vector_type(8)))  short bf16x8;   // 8 x bf16 (4 VGPR)
typedef __attribute__((ext_vector_type(16))) float f32x16;   // MFMA 32x32 acc
typedef __attribute__((ext_vector_type(4)))  int   i32x4;

__device__ __forceinline__ unsigned short f2bf(float x) {    // RNE fp32->bf16
  unsigned u = __float_as_uint(x);
  u += 0x7fffu + ((u >> 16) & 1u);
  return (unsigned short)(u >> 16);
}
__device__ __forceinline__ float bf2f(unsigned short h) {
  return __uint_as_float(((unsigned)h) << 16);
}
__device__ __forceinline__ unsigned pk2bf(float lo, float hi) {
#if defined(__has_builtin)
#if __has_builtin(__builtin_amdgcn_cvt_pk_bf16_f32)
  auto v = __builtin_amdgcn_cvt_pk_bf16_f32(lo, hi);
  unsigned u; __builtin_memcpy(&u, &v, 4); return u;
#else
  return ((unsigned)f2bf(hi) << 16) | (unsigned)f2bf(lo);
#endif
#else
  return ((unsigned)f2bf(hi) << 16) | (unsigned)f2bf(lo);
#endif
}
__device__ __forceinline__ float silu_f(float v) {
  return v * __builtin_amdgcn_rcpf(1.0f + __expf(-v));
}
__device__ __forceinline__ unsigned lo_pack(unsigned x, unsigned y) {
  return __builtin_amdgcn_perm(y, x, 0x05040100u);   // x.lo16 | y.lo16<<16
}
__device__ __forceinline__ unsigned hi_pack(unsigned x, unsigned y) {
  return __builtin_amdgcn_perm(y, x, 0x07060302u);
}

// ---- pack W0/W1/W2 into MFMA B-frag order via LDS transpose (coalesced R+W).
// dest layout: [layer][g(64 cols)][t(32-col tile)][kt][lane][8], K0 padded 134->144.
__global__ void pack_kernel(const float* __restrict__ W0, const float* __restrict__ W1,
                            const float* __restrict__ W2,
                            unsigned short* __restrict__ packW) {
  __shared__ float ldsF[16][257];
  const int s = blockIdx.x, tid = threadIdx.x;
  const float* W; int KT, kmax, base, kt;
  if (s < 9)       { W = W0; KT = 9;  kmax = 134; base = 0;      kt = s; }
  else if (s < 25) { W = W1; KT = 16; kmax = 256; base = 36864;  kt = s - 9; }
  else             { W = W2; KT = 16; kmax = 256; base = 102400; kt = s - 25; }
  const int k0 = kt * 16;
#pragma unroll
  for (int i = 0; i < 8; ++i) {                 // 512 thr x 8 = 16 x 256 floats
    const int idx = i * 512 + tid;
    const int kl = idx >> 8, col = idx & 255;
    const int kg = k0 + kl;
    ldsF[kl][col] = (kg < kmax) ? W[kg * 256 + col] : 0.0f;   // coalesced rows
  }
  __syncthreads();
  const int g = tid >> 7, t = (tid >> 6) & 1, lane = tid & 63;
  const int col = g * 64 + t * 32 + (lane & 31);
  const int kb = 8 * (lane >> 5);
  unsigned u0 = pk2bf(ldsF[kb + 0][col], ldsF[kb + 1][col]);
  unsigned u1 = pk2bf(ldsF[kb + 2][col], ldsF[kb + 3][col]);
  unsigned u2 = pk2bf(ldsF[kb + 4][col], ldsF[kb + 5][col]);
  unsigned u3 = pk2bf(ldsF[kb + 6][col], ldsF[kb + 7][col]);
  unsigned short* dst = packW + base + g * (KT * 1024) + t * (KT * 512) + kt * 512 + lane * 8;
  i32x4 v = { (int)u0, (int)u1, (int)u2, (int)u3 };
  *(i32x4*)dst = v;
}

struct EpiPre {
  float e0t0, e0t1, e15t0, e15t1, bp0, bp1, bn0, bn1, bias0, bias1;
};

// ---------------- one GCN layer: MFMA<->VALU software-interleaved pipeline --------
// Node map: A-row m holds node 32w + sig(m); C/D reg r of lane (q,c) = node 32w+16q+r.
// Group pipeline: K-loop(g) MFMA issues are interleaved 1:1 in source with
// epilogue(g-1) VALU. Boundary exchange = R7 epoch-flag dataflow (no barriers),
// so the interleaved block is branch-free and schedulable.
template <int KT, int LAYER>
__device__ __forceinline__ void gcn_layer(
    const int w, const int lane, const int q, const int c, const int sig,
    const int wp, const int wn, const int ebase,
    const unsigned short* __restrict__ packL,
    const float* __restrict__ BIAS,
    const bf16x8* Aold, bf16x8* Anew,
    unsigned short* bndE, unsigned int* flagsL,
    unsigned int* scr3_w, float* poolw) {
  const float T = 0.33333333333f;
  f32x16 a0[2], a1[2];          // parity-indexed acc (unrolled -> no copies)
  EpiPre ep;
  float ps0 = 0.f, ps1 = 0.f;

  auto spin = [&](int ww, int e) {
    while (__hip_atomic_load(&flagsL[e * 8 + ww], __ATOMIC_ACQUIRE,
                             __HIP_MEMORY_SCOPE_WORKGROUP) == 0u)
      __builtin_amdgcn_s_sleep(1);
  };
  auto publish = [&](int g, const f32x16& C0, const f32x16& C1) {
    unsigned short* myb = bndE + ((ebase + g) * 8 + w) * 128;
    if (q == 0) { myb[c]      = f2bf(C0[0]);  myb[32 + c] = f2bf(C1[0]);  }
    else        { myb[64 + c] = f2bf(C0[15]); myb[96 + c] = f2bf(C1[15]); }
    if (lane == 0)
      __hip_atomic_store(&flagsL[(ebase + g) * 8 + w], 1u, __ATOMIC_RELEASE,
                         __HIP_MEMORY_SCOPE_WORKGROUP);
  };
  auto epi_prep = [&](int pg, const f32x16& P0, const f32x16& P1) {
    const int e = ebase + pg;
    ep.e0t0  = __shfl_xor(P0[0], 32);  ep.e0t1  = __shfl_xor(P1[0], 32);
    ep.e15t0 = __shfl_xor(P0[15], 32); ep.e15t1 = __shfl_xor(P1[15], 32);
    ep.bp0 = bf2f(bndE[(e * 8 + wp) * 128 + 64 + c]);   // node 32w-1
    ep.bp1 = bf2f(bndE[(e * 8 + wp) * 128 + 96 + c]);
    ep.bn0 = bf2f(bndE[(e * 8 + wn) * 128 + c]);        // node 32w+32
    ep.bn1 = bf2f(bndE[(e * 8 + wn) * 128 + 32 + c]);
    ep.bias0 = BIAS[pg * 64 + c]; ep.bias1 = BIAS[pg * 64 + 32 + c];
    ps0 = 0.f; ps1 = 0.f;
  };
  // one epilogue value-pair (node 32w+16q+r, cols C/C+32 of prev group)
  auto epi_iter = [&](int r, const f32x16& P0, const f32x16& P1) {
    float pr0, pr1, nx0, nx1;
    if (r > 0)  { pr0 = P0[r - 1]; pr1 = P1[r - 1]; }
    else        { pr0 = q ? ep.e15t0 : ep.bp0; pr1 = q ? ep.e15t1 : ep.bp1; }
    if (r < 15) { nx0 = P0[r + 1]; nx1 = P1[r + 1]; }
    else        { nx0 = q ? ep.bn0 : ep.e0t0; nx1 = q ? ep.bn1 : ep.e0t1; }
    const float v0 = (pr0 + P0[r] + nx0) * T + ep.bias0;
    const float v1 = (pr1 + P1[r] + nx1) * T + ep.bias1;
    const float y0 = silu_f(v0);
    const float y1 = silu_f(v1);
    if constexpr (LAYER == 2) { ps0 += y0; ps1 += y1; }
    else scr3_w[(16 * q + r) * 34 + c] = pk2bf(y0, y1);   // row = node-local idx
  };
  auto epi_fini = [&](int pg) {
    if constexpr (LAYER == 2) {
      float s0 = ps0 + __shfl_xor(ps0, 32);
      float s1 = ps1 + __shfl_xor(ps1, 32);
      if (q == 0) { poolw[w * 256 + pg * 64 + c]      = s0;
                    poolw[w * 256 + pg * 64 + 32 + c] = s1; }
    } else {
      // rebuild next-layer A-frags (same-wave DS, in-order)
      const unsigned int* sb = scr3_w + sig * 34;
      uint2 d0 = *(const uint2*)(sb + 8 * q + 0);
      uint2 d1 = *(const uint2*)(sb + 8 * q + 2);
      uint2 d2 = *(const uint2*)(sb + 8 * q + 4);
      uint2 d3 = *(const uint2*)(sb + 8 * q + 6);
      uint2 e0 = *(const uint2*)(sb + 16 + 8 * q + 0);
      uint2 e1 = *(const uint2*)(sb + 16 + 8 * q + 2);
      uint2 e2 = *(const uint2*)(sb + 16 + 8 * q + 4);
      uint2 e3 = *(const uint2*)(sb + 16 + 8 * q + 6);
      i32x4 f0 = { (int)lo_pack(d0.x, d0.y), (int)lo_pack(d1.x, d1.y),
                   (int)lo_pack(d2.x, d2.y), (int)lo_pack(d3.x, d3.y) };
      i32x4 f1 = { (int)lo_pack(e0.x, e0.y), (int)lo_pack(e1.x, e1.y),
                   (int)lo_pack(e2.x, e2.y), (int)lo_pack(e3.x, e3.y) };
      i32x4 f2v = { (int)hi_pack(d0.x, d0.y), (int)hi_pack(d1.x, d1.y),
                    (int)hi_pack(d2.x, d2.y), (int)hi_pack(d3.x, d3.y) };
      i32x4 f3 = { (int)hi_pack(e0.x, e0.y), (int)hi_pack(e1.x, e1.y),
                   (int)hi_pack(e2.x, e2.y), (int)hi_pack(e3.x, e3.y) };
      Anew[pg * 4 + 0] = __builtin_bit_cast(bf16x8, f0);
      Anew[pg * 4 + 1] = __builtin_bit_cast(bf16x8, f1);
      Anew[pg * 4 + 2] = __builtin_bit_cast(bf16x8, f2v);
      Anew[pg * 4 + 3] = __builtin_bit_cast(bf16x8, f3);
    }
  };
  // K-loop for group g; when doEpi, 16 epilogue iters of prev group are
  // interleaved 1:1 with the MFMA issue stream (branch-free, constexpr-unrolled)
  auto run_group = [&](int g, f32x16& C0, f32x16& C1,
                       const f32x16& P0, const f32x16& P1, bool doEpi) {
    const bf16x8* wb0 = (const bf16x8*)(packL + g * (KT * 1024));
    const bf16x8* wb1 = (const bf16x8*)(packL + g * (KT * 1024) + KT * 512);
#pragma unroll
    for (int i = 0; i < 16; ++i) { C0[i] = 0.f; C1[i] = 0.f; }
    bf16x8 pb0[2], pb1[2];                      // depth-2 load pipeline
    pb0[0] = wb0[lane]; pb1[0] = wb1[lane];
    if (KT > 1) { pb0[1] = wb0[64 + lane]; pb1[1] = wb1[64 + lane]; }
#pragma unroll
    for (int kt = 0; kt < KT; ++kt) {
      bf16x8 b0 = pb0[kt & 1], b1 = pb1[kt & 1];
      if (kt + 2 < KT) { pb0[kt & 1] = wb0[(kt + 2) * 64 + lane];
                         pb1[kt & 1] = wb1[(kt + 2) * 64 + lane]; }
      C0 = __builtin_amdgcn_mfma_f32_32x32x16_bf16(Aold[kt], b0, C0, 0, 0, 0);
      C1 = __builtin_amdgcn_mfma_f32_32x32x16_bf16(Aold[kt], b1, C1, 0, 0, 0);
      if (doEpi) {
#pragma unroll
        for (int r = (kt * 16) / KT; r < ((kt + 1) * 16) / KT; ++r)
          epi_iter(r, P0, P1);
      }
    }
  };

  // ---- group pipeline ----
  run_group(0, a0[0], a1[0], a0[0], a1[0], false);
  publish(0, a0[0], a1[0]);
#pragma unroll
  for (int g = 1; g <= 3; ++g) {
    const int pg = g - 1, pp = pg & 1, cp = g & 1;
    spin(wp, ebase + pg); spin(wn, ebase + pg);
    epi_prep(pg, a0[pp], a1[pp]);
    run_group(g, a0[cp], a1[cp], a0[pp], a1[pp], true);
    epi_fini(pg);
    publish(g, a0[cp], a1[cp]);
  }
  spin(wp, ebase + 3); spin(wn, ebase + 3);
  epi_prep(3, a0[1], a1[1]);
#pragma unroll
  for (int r = 0; r < 16; ++r) epi_iter(r, a0[1], a1[1]);
  epi_fini(3);
}

// ---------------- main fused kernel: 1 block = 1 graph, 8 waves x 32 nodes ----------
__global__ __launch_bounds__(512, 2) void poly_kernel(
    const float* __restrict__ x, const float* __restrict__ t,
    const float* __restrict__ tw, const float* __restrict__ tb,
    const unsigned short* __restrict__ packW,
    const float* __restrict__ B0, const float* __restrict__ B1,
    const float* __restrict__ B2, float* __restrict__ out) {
  __shared__ __align__(16) unsigned short bndE[12288];   // 24 KiB: 12 epochs x 8 w x 128
  __shared__ unsigned int flagsL[96];                    // per-(epoch,wave) flags
  __shared__ __align__(16) unsigned int   scr3[8 * 1088];// 34 KiB per-wave transpose
  __shared__ float poolL[2048];                          //  8 KiB per-wave pool partials
  __shared__ __align__(16) unsigned short temb_sh[160];  // padded time embedding (bf16)

  const int tid = threadIdx.x;
  const int w = tid >> 6, lane = tid & 63;
  const int q = lane >> 5, c = lane & 31;
  const int wp = (w + 7) & 7, wn = (w + 1) & 7;
  const int b = blockIdx.x;
  const int sig = (c & 3) + 4 * ((c >> 3) & 3) + 16 * ((c >> 2) & 1);

  // zero this wave's 12 epoch flags (published by the MLP's first barrier)
  if (lane < 12) flagsL[lane * 8 + w] = 0;

  // ---- fused time MLP: temb = silu(sinemb(t[b]) @ tw + tb), padded [0x6, ., 0x10] ----
  {
    float* e_sh = (float*)bndE;       // 128 floats scratch (epoch data written later)
    float* part = (float*)scr3;       // 512 float partials
    if (tid < 128) {
      const float tv = t[b];
      const int i = tid & 63;
      const float f = expf(-0.14619588396823767f * (float)i);  // log(1e4)/63
      const float ang = tv * f;
      e_sh[tid] = (tid < 64) ? sinf(ang) : cosf(ang);
    }
    __syncthreads();
    {
      const int j = tid & 127, p = tid >> 7;   // 4-way k-split over the block
      float a = 0.f;
#pragma unroll 8
      for (int kk = 0; kk < 32; ++kk) {
        const int k = p * 32 + kk;
        a += e_sh[k] * tw[k * 128 + j];
      }
      part[tid] = a;
    }
    __syncthreads();
    if (tid < 128) {
      const float a = tb[tid] + part[tid] + part[128 + tid] + part[256 + tid] + part[384 + tid];
      temb_sh[6 + tid] = f2bf(silu_f(a));
      if (tid < 6)  temb_sh[tid] = 0;
      if (tid < 10) temb_sh[134 + tid] = 0;
    }
    __syncthreads();   // temb + zeroed flags visible to all waves
  }

  // layer-0 A frags: [coords(2), pe(4), temb(128), pad0(10)] = K 144
  bf16x8 A0[9], A1[16], A2[16];
  {
#pragma unroll
    for (int kt = 0; kt < 9; ++kt)
      A0[kt] = *(const bf16x8*)(temb_sh + kt * 16 + q * 8);
    if (q == 0) {  // k=0..5 live in q==0 lanes of k-tile 0; A-row m=c holds node 32w+sig
      const int n = w * 32 + sig;
      const float2 xy = ((const float2*)x)[b * 256 + n];
      const float th = 0.024543692605870074f * (float)n;   // 2*pi/256
      A0[0][0] = (short)f2bf(xy.x);
      A0[0][1] = (short)f2bf(xy.y);
      A0[0][2] = (short)f2bf(sinf(th));
      A0[0][3] = (short)f2bf(cosf(th));
      A0[0][4] = (short)f2bf(sinf(2.f * th));
      A0[0][5] = (short)f2bf(cosf(2.f * th));
    }
  }

  unsigned int* scr3_w = scr3 + w * 1088;
  gcn_layer< 9, 0>(w, lane, q, c, sig, wp, wn, 0, packW,          B0, A0, A1,
                   bndE, flagsL, scr3_w, poolL);
  gcn_layer<16, 1>(w, lane, q, c, sig, wp, wn, 4, packW + 36864,  B1, A1, A2,
                   bndE, flagsL, scr3_w, poolL);
  gcn_layer<16, 2>(w, lane, q, c, sig, wp, wn, 8, packW + 102400, B2, A2, A1,
                   bndE, flagsL, scr3_w, poolL);

  __syncthreads();   // the single closing barrier before the pooled reduction
  if (tid < 256) {
    float s = 0.f;
#pragma unroll
    for (int ww = 0; ww < 8; ++ww) s += poolL[ww * 256 + tid];
    out[b * 256 + tid] = s * (1.f / 256.f);
  }
}

// ---------------- launch ----------------
extern "C" void kernel_launch(void* const* d_in, const int* in_sizes, int n_in,
                              void* d_out, int out_size, void* d_ws, size_t ws_size,
                              hipStream_t stream) {
  const float* x  = (const float*)d_in[0];
  const float* t  = (const float*)d_in[1];
  const float* tw = (const float*)d_in[2];
  const float* tb = (const float*)d_in[3];
  const float* W0 = (const float*)d_in[4];
  const float* b0 = (const float*)d_in[5];
  const float* W1 = (const float*)d_in[6];
  const float* b1 = (const float*)d_in[7];
  const float* W2 = (const float*)d_in[8];
  const float* b2 = (const float*)d_in[9];

  unsigned short* packW = (unsigned short*)d_ws;   // 167936 shorts
  float* out = (float*)d_out;

  pack_kernel<<<41, 512, 0, stream>>>(W0, W1, W2, packW);
  poly_kernel<<<1024, 512, 0, stream>>>(x, t, tw, tb, packW, b0, b1, b2, out);
}